// Round 1
// baseline (1067.918 us; speedup 1.0000x reference)
//
#include <hip/hip_runtime.h>
#include <hip/hip_bf16.h>
#include <cstdio>

// ---------------------------------------------------------------------------
// LSTMDecoder: B=32, T=64 (63 steps), H=512, V=32000
// Inputs: 0 enc(32,512) 1 captions(32,64)i32 2 emb(32000,512) 3 W_ih(2048,1024)
//         4 W_hh(2048,512) 5 b_ih(2048) 6 b_hh(2048) 7 W_out(32000,512) 8 b_out(32000)
// Out: logits(32,63,32000) f32, caption_probs(32,63), pred_captions(32,63 as f32)
// ---------------------------------------------------------------------------

typedef _Float16 half8_t __attribute__((ext_vector_type(8)));
typedef float f32x4_t __attribute__((ext_vector_type(4)));
typedef _Float16 half2_t __attribute__((ext_vector_type(2)));

#define H 512
#define BATCH 32
#define TSTEPS 63
#define G4 2048
#define V 32000

// ---------------- K1: gxe[b][j] = enc[b]·W_ih[j, :512] + b_ih[j] + b_hh[j] ---
__global__ void k_gxe(const float* __restrict__ enc, const float* __restrict__ W_ih,
                      const float* __restrict__ b_ih, const float* __restrict__ b_hh,
                      float* __restrict__ gxe) {
  __shared__ float sW[16 * 512];      // 32 KB
  __shared__ float sP[16 * 8 * 32];   // 16 KB
  int tid = threadIdx.x;
  int jg = blockIdx.x;                // 128 blocks * 16 rows
  #pragma unroll
  for (int rep = 0; rep < 8; ++rep) {
    int q = tid + rep * 256;          // 2048 float4 chunks
    int row = q >> 7, c4 = q & 127;
    float4 v = *(const float4*)(W_ih + (size_t)(jg * 16 + row) * 1024 + c4 * 4);
    *(float4*)(sW + row * 512 + c4 * 4) = v;
  }
  int b = tid & 31, kg = tid >> 5;
  float hreg[64];
  const float* ep = enc + b * 512 + kg * 64;
  #pragma unroll
  for (int i = 0; i < 64; ++i) hreg[i] = ep[i];
  __syncthreads();
  #pragma unroll
  for (int r = 0; r < 16; ++r) {
    float acc = 0.f;
    const float* wp = sW + r * 512 + kg * 64;
    #pragma unroll
    for (int i = 0; i < 64; ++i) acc += hreg[i] * wp[i];
    sP[(r * 8 + kg) * 32 + b] = acc;
  }
  __syncthreads();
  for (int o = tid; o < 512; o += 256) {
    int r = o >> 5, bb = o & 31;
    float s = 0.f;
    #pragma unroll
    for (int k2 = 0; k2 < 8; ++k2) s += sP[(r * 8 + k2) * 32 + bb];
    int j = jg * 16 + r;
    gxe[bb * 2048 + j] = s + b_ih[j] + b_hh[j];
  }
}

// ---------------- f32 -> f16 convert (W_out) -------------------------------
__global__ void k_f32_to_f16(const float* __restrict__ src, _Float16* __restrict__ dst) {
  size_t i = ((size_t)blockIdx.x * 256 + threadIdx.x) * 8;
  float4 a = *(const float4*)(src + i);
  float4 b = *(const float4*)(src + i + 4);
  half8_t o;
  o[0] = (_Float16)a.x; o[1] = (_Float16)a.y; o[2] = (_Float16)a.z; o[3] = (_Float16)a.w;
  o[4] = (_Float16)b.x; o[5] = (_Float16)b.y; o[6] = (_Float16)b.z; o[7] = (_Float16)b.w;
  *(half8_t*)(dst + i) = o;
}

// ---------------- K2: ginT[t][j][b] = gxe[b][j] + emb[cap[b][t]]·W_ih[j,512:] ---
__global__ void k_gin(const float* __restrict__ emb, const int* __restrict__ caps,
                      const float* __restrict__ W_ih, const float* __restrict__ gxe,
                      float* __restrict__ ginT) {
  __shared__ float sA[64 * 36];
  __shared__ float sB[64 * 36];
  int tid = threadIdx.x;
  int nb = blockIdx.x;  // 32 N-tiles (gate dim)
  int mb = blockIdx.y;  // 32 M-tiles (t*32+b)
  float acc[4][4] = {};
  int tx = tid & 15, ty = tid >> 4;
  for (int k0 = 0; k0 < 512; k0 += 32) {
    __syncthreads();
    #pragma unroll
    for (int rep = 0; rep < 2; ++rep) {
      int q = tid + rep * 256;
      int row = q >> 3, c4 = q & 7;
      int m = mb * 64 + row;
      int t = m >> 5, b = m & 31;
      if (t > 62) t = 62;
      int tok = caps[b * 64 + t];
      float4 v = *(const float4*)(emb + (size_t)tok * 512 + k0 + c4 * 4);
      *(float4*)(sA + row * 36 + c4 * 4) = v;
      int n = nb * 64 + row;
      float4 w = *(const float4*)(W_ih + (size_t)n * 1024 + 512 + k0 + c4 * 4);
      *(float4*)(sB + row * 36 + c4 * 4) = w;
    }
    __syncthreads();
    #pragma unroll
    for (int kk = 0; kk < 32; ++kk) {
      float a4[4], b4[4];
      #pragma unroll
      for (int i = 0; i < 4; ++i) a4[i] = sA[(ty * 4 + i) * 36 + kk];
      #pragma unroll
      for (int j = 0; j < 4; ++j) b4[j] = sB[(tx * 4 + j) * 36 + kk];
      #pragma unroll
      for (int i = 0; i < 4; ++i)
        #pragma unroll
        for (int j = 0; j < 4; ++j) acc[i][j] += a4[i] * b4[j];
    }
  }
  #pragma unroll
  for (int i = 0; i < 4; ++i) {
    int m = mb * 64 + ty * 4 + i;
    if (m >= 2016) break;
    int t = m >> 5, b = m & 31;
    #pragma unroll
    for (int j = 0; j < 4; ++j) {
      int n = nb * 64 + tx * 4 + j;
      ginT[(size_t)t * 65536 + (size_t)n * 32 + b] = acc[i][j] + gxe[b * 2048 + n];
    }
  }
}

// ---------------- K3: one LSTM step (launched 63x) -------------------------
// block kb owns k in [kb*2, kb*2+2); gate rows r = g*2+kl -> j = g*512 + kb*2 + kl
__global__ void k_step(const float* __restrict__ hT_prev, const float* __restrict__ W_hh,
                       const float* __restrict__ ginT_t, float* __restrict__ cT,
                       float* __restrict__ hT_out, _Float16* __restrict__ hf16_t) {
  __shared__ float sW[8 * 512];     // 16 KB
  __shared__ float sP[8 * 8 * 32];  // 8 KB
  __shared__ float sG[8 * 32];      // 1 KB
  int tid = threadIdx.x, kb = blockIdx.x;
  int kbase = kb * 2;
  #pragma unroll
  for (int rep = 0; rep < 4; ++rep) {
    int q = tid + rep * 256;        // 1024 float4 chunks
    int row = q >> 7, c4 = q & 127;
    int j = (row >> 1) * 512 + kbase + (row & 1);
    float4 v = *(const float4*)(W_hh + (size_t)j * 512 + c4 * 4);
    *(float4*)(sW + row * 512 + c4 * 4) = v;
  }
  int b = tid & 31, kg = tid >> 5;
  float hreg[64];
  const float* hp = hT_prev + kg * 64 * 32 + b;
  #pragma unroll
  for (int i = 0; i < 64; ++i) hreg[i] = hp[i * 32];
  __syncthreads();
  #pragma unroll
  for (int r = 0; r < 8; ++r) {
    float acc = 0.f;
    const float* wp = sW + r * 512 + kg * 64;
    #pragma unroll
    for (int i = 0; i < 64; ++i) acc += hreg[i] * wp[i];
    sP[(r * 8 + kg) * 32 + b] = acc;
  }
  __syncthreads();
  {
    int r = tid >> 5;
    float s = 0.f;
    #pragma unroll
    for (int k2 = 0; k2 < 8; ++k2) s += sP[(r * 8 + k2) * 32 + b];
    int j = (r >> 1) * 512 + kbase + (r & 1);
    sG[r * 32 + b] = s + ginT_t[(size_t)j * 32 + b];
  }
  __syncthreads();
  if (tid < 64) {
    int kl = tid >> 5;
    int k = kbase + kl;
    float gi = sG[(0 * 2 + kl) * 32 + b];
    float gf = sG[(1 * 2 + kl) * 32 + b];
    float gg = sG[(2 * 2 + kl) * 32 + b];
    float go = sG[(3 * 2 + kl) * 32 + b];
    float si = 1.f / (1.f + expf(-gi));
    float sf = 1.f / (1.f + expf(-gf));
    float so = 1.f / (1.f + expf(-go));
    float tg = tanhf(gg);
    float c = sf * cT[k * 32 + b] + si * tg;
    float h = so * tanhf(c);
    cT[k * 32 + b] = c;
    hT_out[k * 32 + b] = h;
    hf16_t[(size_t)b * 512 + k] = (_Float16)h;
  }
}

// ---------------- K4: logits = Hf16 @ Woutf16^T + bias, fused tile-max ------
#define ALD 40  // padded LDS row (f16 elems) for 32-k tile
__global__ void k_logits(const _Float16* __restrict__ A,  // [2048][512]
                         const _Float16* __restrict__ B,  // [32000][512]
                         const float* __restrict__ bias,
                         float* __restrict__ out,
                         float* __restrict__ tmv) {
  __shared__ _Float16 sA[128 * ALD];
  __shared__ _Float16 sB[128 * ALD];
  __shared__ float redv[128 * 2];
  int tid = threadIdx.x;
  int nb = blockIdx.x;   // 250
  int mb = blockIdx.y;   // 16
  int lane = tid & 63, wave = tid >> 6;
  int wm = wave >> 1, wn = wave & 1;
  const int m0 = mb * 128, n0 = nb * 128;
  f32x4_t acc[4][4] = {};
  int rA = lane & 15, q8 = lane >> 4;
  for (int k0 = 0; k0 < 512; k0 += 32) {
    __syncthreads();
    #pragma unroll
    for (int rep = 0; rep < 2; ++rep) {
      int q = tid + rep * 256;   // 512 chunks of 8 f16
      int row = q >> 2, seg = q & 3;
      *(half8_t*)(sA + row * ALD + seg * 8) =
          *(const half8_t*)(A + (size_t)(m0 + row) * 512 + k0 + seg * 8);
      *(half8_t*)(sB + row * ALD + seg * 8) =
          *(const half8_t*)(B + (size_t)(n0 + row) * 512 + k0 + seg * 8);
    }
    __syncthreads();
    half8_t afr[4], bfr[4];
    #pragma unroll
    for (int i = 0; i < 4; ++i) {
      afr[i] = *(const half8_t*)(sA + (wm * 64 + i * 16 + rA) * ALD + q8 * 8);
      bfr[i] = *(const half8_t*)(sB + (wn * 64 + i * 16 + rA) * ALD + q8 * 8);
    }
    #pragma unroll
    for (int i = 0; i < 4; ++i)
      #pragma unroll
      for (int j = 0; j < 4; ++j)
        acc[i][j] = __builtin_amdgcn_mfma_f32_16x16x32_f16(afr[i], bfr[j], acc[i][j], 0, 0, 0);
  }
  // epilogue: bias add, store, per-row tile max (over this block's 128 cols)
  #pragma unroll
  for (int i = 0; i < 4; ++i) {
    #pragma unroll
    for (int p = 0; p < 4; ++p) {
      int m_loc = wm * 64 + i * 16 + q8 * 4 + p;
      int m = m0 + m_loc;
      float vmax = -3.4e38f;
      float vs[4];
      #pragma unroll
      for (int j = 0; j < 4; ++j) {
        int n_loc = wn * 64 + j * 16 + rA;
        float v = acc[i][j][p] + bias[n0 + n_loc];
        vs[j] = v;
        vmax = fmaxf(vmax, v);
      }
      if (m < 2016) {
        int t = m >> 5, bb = m & 31;
        float* orow = out + (size_t)(bb * 63 + t) * 32000 + n0;
        #pragma unroll
        for (int j = 0; j < 4; ++j) orow[wn * 64 + j * 16 + rA] = vs[j];
      }
      #pragma unroll
      for (int o = 1; o < 16; o <<= 1) vmax = fmaxf(vmax, __shfl_xor(vmax, o));
      if (rA == 0) redv[m_loc * 2 + wn] = vmax;
    }
  }
  __syncthreads();
  if (tid < 128) {
    int m = m0 + tid;
    if (m < 2016) {
      float bv = fmaxf(redv[tid * 2], redv[tid * 2 + 1]);
      tmv[(size_t)m * 256 + nb] = bv;
    }
  }
}

// ---------------- K5: exact max/argmax fixup (1 wave per (b,t) row) --------
__global__ void k_final(const float* __restrict__ tmv, const float* __restrict__ HallT,
                        const float* __restrict__ Wout, const float* __restrict__ bias,
                        const float* __restrict__ logits,
                        float* __restrict__ probs, float* __restrict__ preds) {
  int m = blockIdx.x;  // 0..2015, m = t*32 + b
  int t = m >> 5, b = m & 31;
  int lane = threadIdx.x;
  // approx global max over 250 tile maxes
  float mx = -3.4e38f;
  for (int nb = lane; nb < 250; nb += 64) mx = fmaxf(mx, tmv[(size_t)m * 256 + nb]);
  #pragma unroll
  for (int o = 1; o < 64; o <<= 1) mx = fmaxf(mx, __shfl_xor(mx, o));
  // h row + norm for sound error margin: |approx-exact| <= 2^-10 * ||h|| * ||w||max
  const float* hrow = HallT + (size_t)t * 16384 + b;
  float hl[8];
  float s2 = 0.f;
  #pragma unroll
  for (int i = 0; i < 8; ++i) {
    float hv = hrow[(lane * 8 + i) * 32];
    hl[i] = hv;
    s2 += hv * hv;
  }
  #pragma unroll
  for (int o = 1; o < 64; o <<= 1) s2 += __shfl_xor(s2, o);
  float marg = 0.0016f * sqrtf(s2) + 3e-4f;   // 2^-10 * 1.3 * ||h|| + slack
  float thr = mx - 2.f * marg;
  float bestv = -3.4e38f;
  int besti = 0x7fffffff;
  const float* lrow = logits + (size_t)(b * 63 + t) * 32000;
  for (int nb = 0; nb < 250; ++nb) {
    if (tmv[(size_t)m * 256 + nb] < thr) continue;
    #pragma unroll
    for (int rep = 0; rep < 2; ++rep) {
      int n = nb * 128 + rep * 64 + lane;
      float av = lrow[n];
      unsigned long long mask = __ballot(av >= thr);
      while (mask) {
        int ln = __ffsll((unsigned long long)mask) - 1;
        mask &= mask - 1;
        int nn = __shfl(n, ln);
        const float* wr = Wout + (size_t)nn * 512;
        float p = 0.f;
        #pragma unroll
        for (int i = 0; i < 8; ++i) p += hl[i] * wr[lane * 8 + i];
        #pragma unroll
        for (int o = 1; o < 64; o <<= 1) p += __shfl_xor(p, o);
        p += bias[nn];
        if (p > bestv || (p == bestv && nn < besti)) { bestv = p; besti = nn; }
      }
    }
  }
  if (lane == 0) {
    probs[b * 63 + t] = bestv;
    preds[b * 63 + t] = (float)besti;
  }
}

// ---------------------------------------------------------------------------
extern "C" void kernel_launch(void* const* d_in, const int* in_sizes, int n_in,
                              void* d_out, int out_size, void* d_ws, size_t ws_size,
                              hipStream_t stream) {
  const float* enc   = (const float*)d_in[0];
  const int*   caps  = (const int*)d_in[1];
  const float* emb   = (const float*)d_in[2];
  const float* W_ih  = (const float*)d_in[3];
  const float* W_hh  = (const float*)d_in[4];
  const float* b_ih  = (const float*)d_in[5];
  const float* b_hh  = (const float*)d_in[6];
  const float* W_out = (const float*)d_in[7];
  const float* b_out = (const float*)d_in[8];
  float* out = (float*)d_out;

  // ws layout (bytes)
  char* ws = (char*)d_ws;
  const size_t off_gin  = 0;                       // 64*2048*32 f32 = 16 MB
  const size_t off_gxe  = 16777216;                // 32*2048 f32
  const size_t off_hall = off_gxe + 262144;        // 64*16384 f32 = 4 MB  [t][k][b]
  const size_t off_hf16 = off_hall + 4194304;      // 2048*512 f16 = 2 MB  [m][k]
  const size_t off_c    = off_hf16 + 2097152;      // 16384 f32
  const size_t off_hz   = off_c + 65536;           // 16384 f32 (zeros)
  const size_t off_tmv  = off_hz + 65536;          // 2048*256 f32 = 2 MB
  const size_t off_wf16 = off_tmv + 2097152;       // 32000*512 f16 = 32.768 MB
  const size_t need     = off_wf16 + 32768000;
  if (ws_size < need) {
    fprintf(stderr, "kernel_launch: ws_size %zu < needed %zu\n", ws_size, need);
    return;
  }
  float*     ginT  = (float*)(ws + off_gin);
  float*     gxe   = (float*)(ws + off_gxe);
  float*     HallT = (float*)(ws + off_hall);
  _Float16*  Hf16  = (_Float16*)(ws + off_hf16);
  float*     cT    = (float*)(ws + off_c);
  float*     hzero = (float*)(ws + off_hz);
  float*     tmv   = (float*)(ws + off_tmv);
  _Float16*  Wf16  = (_Float16*)(ws + off_wf16);

  // zero c0 and h0 (ws is re-poisoned before every call)
  hipMemsetAsync(ws + off_c, 0, 131072, stream);

  k_gxe<<<128, 256, 0, stream>>>(enc, W_ih, b_ih, b_hh, gxe);
  k_f32_to_f16<<<8000, 256, 0, stream>>>(W_out, Wf16);   // 32000*512 / 2048 per block
  k_gin<<<dim3(32, 32), 256, 0, stream>>>(emb, caps, W_ih, gxe, ginT);

  for (int t = 0; t < 63; ++t) {
    const float* hprev = (t == 0) ? hzero : (HallT + (size_t)(t - 1) * 16384);
    k_step<<<256, 256, 0, stream>>>(hprev, W_hh, ginT + (size_t)t * 65536, cT,
                                    HallT + (size_t)t * 16384, Hf16 + (size_t)t * 16384);
  }

  k_logits<<<dim3(250, 16), 256, 0, stream>>>(Hf16, Wf16, b_out, out, tmv);

  float* probs = out + (size_t)2016 * 32000;
  float* preds = probs + 2016;
  k_final<<<2016, 64, 0, stream>>>(tmv, HallT, W_out, b_out, out, probs, preds);
}

// Round 2
// 917.607 us; speedup vs baseline: 1.1638x; 1.1638x over previous
//
#include <hip/hip_runtime.h>
#include <hip/hip_bf16.h>
#include <cstdio>

// ---------------------------------------------------------------------------
// LSTMDecoder: B=32, T=64 (63 steps), H=512, V=32000
// Inputs: 0 enc(32,512) 1 captions(32,64)i32 2 emb(32000,512) 3 W_ih(2048,1024)
//         4 W_hh(2048,512) 5 b_ih(2048) 6 b_hh(2048) 7 W_out(32000,512) 8 b_out(32000)
// Out: logits(32,63,32000) f32, caption_probs(32,63), pred_captions(32,63 as f32)
// ---------------------------------------------------------------------------

typedef _Float16 half8_t __attribute__((ext_vector_type(8)));
typedef _Float16 half4_t __attribute__((ext_vector_type(4)));
typedef float f32x4_t __attribute__((ext_vector_type(4)));

#define H 512
#define BATCH 32
#define TSTEPS 63
#define G4 2048
#define V 32000

// ---------------- K1: gxe[b][j] = enc[b]·W_ih[j, :512] + b_ih[j] + b_hh[j] ---
__global__ void k_gxe(const float* __restrict__ enc, const float* __restrict__ W_ih,
                      const float* __restrict__ b_ih, const float* __restrict__ b_hh,
                      float* __restrict__ gxe) {
  __shared__ float sW[16 * 512];      // 32 KB
  __shared__ float sP[16 * 8 * 32];   // 16 KB
  int tid = threadIdx.x;
  int jg = blockIdx.x;                // 128 blocks * 16 rows
  #pragma unroll
  for (int rep = 0; rep < 8; ++rep) {
    int q = tid + rep * 256;          // 2048 float4 chunks
    int row = q >> 7, c4 = q & 127;
    float4 v = *(const float4*)(W_ih + (size_t)(jg * 16 + row) * 1024 + c4 * 4);
    *(float4*)(sW + row * 512 + c4 * 4) = v;
  }
  int b = tid & 31, kg = tid >> 5;
  float hreg[64];
  const float* ep = enc + b * 512 + kg * 64;
  #pragma unroll
  for (int i = 0; i < 64; ++i) hreg[i] = ep[i];
  __syncthreads();
  #pragma unroll
  for (int r = 0; r < 16; ++r) {
    float acc = 0.f;
    const float* wp = sW + r * 512 + kg * 64;
    #pragma unroll
    for (int i = 0; i < 64; ++i) acc += hreg[i] * wp[i];
    sP[(r * 8 + kg) * 32 + b] = acc;
  }
  __syncthreads();
  for (int o = tid; o < 512; o += 256) {
    int r = o >> 5, bb = o & 31;
    float s = 0.f;
    #pragma unroll
    for (int k2 = 0; k2 < 8; ++k2) s += sP[(r * 8 + k2) * 32 + bb];
    int j = jg * 16 + r;
    gxe[bb * 2048 + j] = s + b_ih[j] + b_hh[j];
  }
}

// ---------------- f32 -> f16 convert (W_out) -------------------------------
__global__ void k_f32_to_f16(const float* __restrict__ src, _Float16* __restrict__ dst) {
  size_t i = ((size_t)blockIdx.x * 256 + threadIdx.x) * 8;
  float4 a = *(const float4*)(src + i);
  float4 b = *(const float4*)(src + i + 4);
  half8_t o;
  o[0] = (_Float16)a.x; o[1] = (_Float16)a.y; o[2] = (_Float16)a.z; o[3] = (_Float16)a.w;
  o[4] = (_Float16)b.x; o[5] = (_Float16)b.y; o[6] = (_Float16)b.z; o[7] = (_Float16)b.w;
  *(half8_t*)(dst + i) = o;
}

// ---------------- prep: split W_ih[:,512:1024] into f16 hi+lo --------------
__global__ void k_prep_w(const float* __restrict__ W_ih, _Float16* __restrict__ hi,
                         _Float16* __restrict__ lo) {
  size_t idx = ((size_t)blockIdx.x * 256 + threadIdx.x) * 4;  // 1M elems / 4
  int row = (int)(idx >> 9), col = (int)(idx & 511);
  float4 v = *(const float4*)(W_ih + (size_t)row * 1024 + 512 + col);
  half4_t vh, vl;
  vh[0] = (_Float16)v.x; vl[0] = (_Float16)(v.x - (float)vh[0]);
  vh[1] = (_Float16)v.y; vl[1] = (_Float16)(v.y - (float)vh[1]);
  vh[2] = (_Float16)v.z; vl[2] = (_Float16)(v.z - (float)vh[2]);
  vh[3] = (_Float16)v.w; vl[3] = (_Float16)(v.w - (float)vh[3]);
  *(half4_t*)(hi + idx) = vh;
  *(half4_t*)(lo + idx) = vl;
}

// ---------------- prep: gather emb rows per (t,b), split hi+lo -------------
__global__ void k_prep_x(const float* __restrict__ emb, const int* __restrict__ caps,
                         _Float16* __restrict__ hi, _Float16* __restrict__ lo) {
  int m = blockIdx.x * 4 + (threadIdx.x >> 6);  // 512 blocks -> m in [0,2048)
  int lane = threadIdx.x & 63;
  size_t o = (size_t)m * 512 + lane * 8;
  half8_t vh = {}, vl = {};
  if (m < 2016) {
    int t = m >> 5, b = m & 31;
    int tok = caps[b * 64 + t];
    const float* src = emb + (size_t)tok * 512 + lane * 8;
    float4 a = *(const float4*)(src);
    float4 c = *(const float4*)(src + 4);
    float vs[8] = {a.x, a.y, a.z, a.w, c.x, c.y, c.z, c.w};
    #pragma unroll
    for (int i = 0; i < 8; ++i) {
      vh[i] = (_Float16)vs[i];
      vl[i] = (_Float16)(vs[i] - (float)vh[i]);
    }
  }
  *(half8_t*)(hi + o) = vh;
  *(half8_t*)(lo + o) = vl;
}

// ---------------- K2: ginT[t][j][b] via split-f16 MFMA ---------------------
// A = W_ih-emb-half rows (gate j, M-dim), B = gathered emb rows (m=t*32+b, N-dim)
// acc = Ahi*Bhi + Ahi*Blo + Alo*Bhi  (lo*lo dropped, <=2^-22 rel)
#define ALD 40
__global__ void k_gin_mfma(const _Float16* __restrict__ Whi, const _Float16* __restrict__ Wlo,
                           const _Float16* __restrict__ Xhi, const _Float16* __restrict__ Xlo,
                           const float* __restrict__ gxe, float* __restrict__ ginT) {
  __shared__ _Float16 sAhi[128 * ALD];
  __shared__ _Float16 sAlo[128 * ALD];
  __shared__ _Float16 sBhi[128 * ALD];
  __shared__ _Float16 sBlo[128 * ALD];
  __shared__ float sGxe[32 * 132];   // gxe[b][j_loc], pad 132 -> 2-way banks
  int tid = threadIdx.x;
  int nb = blockIdx.x;   // 16 tiles over m
  int mb = blockIdx.y;   // 16 tiles over gate j
  int lane = tid & 63, wave = tid >> 6;
  int wm = wave >> 1, wn = wave & 1;
  const int m0 = mb * 128, n0 = nb * 128;
  int rA = lane & 15, q8 = lane >> 4;
  // preload gxe slice: 32 b x 128 j_loc
  for (int q = tid; q < 1024; q += 256) {
    int b = q >> 5, c4 = q & 31;
    float4 v = *(const float4*)(gxe + (size_t)b * 2048 + m0 + c4 * 4);
    float* d = sGxe + b * 132 + c4 * 4;
    d[0] = v.x; d[1] = v.y; d[2] = v.z; d[3] = v.w;
  }
  f32x4_t acc[4][4] = {};
  for (int k0 = 0; k0 < 512; k0 += 32) {
    __syncthreads();
    #pragma unroll
    for (int rep = 0; rep < 8; ++rep) {
      int q = rep * 256 + tid;             // 2048 chunks of 8 f16
      int buf = q >> 9, r = q & 511, row = r >> 2, seg = r & 3;
      const _Float16* gsrc;
      _Float16* ldst;
      if (buf == 0)      { gsrc = Whi + (size_t)(m0 + row) * 512; ldst = sAhi; }
      else if (buf == 1) { gsrc = Wlo + (size_t)(m0 + row) * 512; ldst = sAlo; }
      else if (buf == 2) { gsrc = Xhi + (size_t)(n0 + row) * 512; ldst = sBhi; }
      else               { gsrc = Xlo + (size_t)(n0 + row) * 512; ldst = sBlo; }
      *(half8_t*)(ldst + row * ALD + seg * 8) = *(const half8_t*)(gsrc + k0 + seg * 8);
    }
    __syncthreads();
    half8_t ah[4], al[4], bh[4], bl[4];
    #pragma unroll
    for (int i = 0; i < 4; ++i) {
      int ra = (wm * 64 + i * 16 + rA) * ALD + q8 * 8;
      ah[i] = *(const half8_t*)(sAhi + ra);
      al[i] = *(const half8_t*)(sAlo + ra);
      int rb = (wn * 64 + i * 16 + rA) * ALD + q8 * 8;
      bh[i] = *(const half8_t*)(sBhi + rb);
      bl[i] = *(const half8_t*)(sBlo + rb);
    }
    #pragma unroll
    for (int i = 0; i < 4; ++i)
      #pragma unroll
      for (int j = 0; j < 4; ++j) {
        acc[i][j] = __builtin_amdgcn_mfma_f32_16x16x32_f16(ah[i], bh[j], acc[i][j], 0, 0, 0);
        acc[i][j] = __builtin_amdgcn_mfma_f32_16x16x32_f16(ah[i], bl[j], acc[i][j], 0, 0, 0);
        acc[i][j] = __builtin_amdgcn_mfma_f32_16x16x32_f16(al[i], bh[j], acc[i][j], 0, 0, 0);
      }
  }
  // epilogue: add gxe, store ginT[t][j][b] (b-contiguous per 16-lane group)
  #pragma unroll
  for (int i = 0; i < 4; ++i) {
    #pragma unroll
    for (int p = 0; p < 4; ++p) {
      int jg_loc = wm * 64 + i * 16 + q8 * 4 + p;
      int jg = m0 + jg_loc;
      #pragma unroll
      for (int j = 0; j < 4; ++j) {
        int m = n0 + wn * 64 + j * 16 + rA;
        if (m < 2016) {
          int t = m >> 5, b = m & 31;
          ginT[(size_t)t * 65536 + (size_t)jg * 32 + b] = acc[i][j][p] + sGxe[b * 132 + jg_loc];
        }
      }
    }
  }
}

// ---------------- K3: one LSTM step (launched 63x) -------------------------
__global__ void k_step(const float* __restrict__ hT_prev, const float* __restrict__ W_hh,
                       const float* __restrict__ ginT_t, float* __restrict__ cT,
                       float* __restrict__ hT_out, _Float16* __restrict__ hf16_t) {
  __shared__ float sW[8 * 512];     // 16 KB
  __shared__ float sP[8 * 8 * 32];  // 8 KB
  __shared__ float sG[8 * 32];      // 1 KB
  int tid = threadIdx.x, kb = blockIdx.x;
  int kbase = kb * 2;
  #pragma unroll
  for (int rep = 0; rep < 4; ++rep) {
    int q = tid + rep * 256;        // 1024 float4 chunks
    int row = q >> 7, c4 = q & 127;
    int j = (row >> 1) * 512 + kbase + (row & 1);
    float4 v = *(const float4*)(W_hh + (size_t)j * 512 + c4 * 4);
    *(float4*)(sW + row * 512 + c4 * 4) = v;
  }
  int b = tid & 31, kg = tid >> 5;
  float hreg[64];
  const float* hp = hT_prev + kg * 64 * 32 + b;
  #pragma unroll
  for (int i = 0; i < 64; ++i) hreg[i] = hp[i * 32];
  __syncthreads();
  #pragma unroll
  for (int r = 0; r < 8; ++r) {
    float acc = 0.f;
    const float* wp = sW + r * 512 + kg * 64;
    #pragma unroll
    for (int i = 0; i < 64; ++i) acc += hreg[i] * wp[i];
    sP[(r * 8 + kg) * 32 + b] = acc;
  }
  __syncthreads();
  {
    int r = tid >> 5;
    float s = 0.f;
    #pragma unroll
    for (int k2 = 0; k2 < 8; ++k2) s += sP[(r * 8 + k2) * 32 + b];
    int j = (r >> 1) * 512 + kbase + (r & 1);
    sG[r * 32 + b] = s + ginT_t[(size_t)j * 32 + b];
  }
  __syncthreads();
  if (tid < 64) {
    int kl = tid >> 5;
    int k = kbase + kl;
    float gi = sG[(0 * 2 + kl) * 32 + b];
    float gf = sG[(1 * 2 + kl) * 32 + b];
    float gg = sG[(2 * 2 + kl) * 32 + b];
    float go = sG[(3 * 2 + kl) * 32 + b];
    float si = 1.f / (1.f + expf(-gi));
    float sf = 1.f / (1.f + expf(-gf));
    float so = 1.f / (1.f + expf(-go));
    float tg = tanhf(gg);
    float c = sf * cT[k * 32 + b] + si * tg;
    float h = so * tanhf(c);
    cT[k * 32 + b] = c;
    hT_out[k * 32 + b] = h;
    hf16_t[(size_t)b * 512 + k] = (_Float16)h;
  }
}

// ---------------- K4: logits = Hf16 @ Woutf16^T + bias, fused tile-max ------
__global__ void k_logits(const _Float16* __restrict__ A,  // [2048][512]
                         const _Float16* __restrict__ B,  // [32000][512]
                         const float* __restrict__ bias,
                         float* __restrict__ out,
                         float* __restrict__ tmv) {
  __shared__ _Float16 sA[128 * ALD];
  __shared__ _Float16 sB[128 * ALD];
  __shared__ float redv[128 * 2];
  int tid = threadIdx.x;
  int nb = blockIdx.x;   // 250
  int mb = blockIdx.y;   // 16
  int lane = tid & 63, wave = tid >> 6;
  int wm = wave >> 1, wn = wave & 1;
  const int m0 = mb * 128, n0 = nb * 128;
  f32x4_t acc[4][4] = {};
  int rA = lane & 15, q8 = lane >> 4;
  for (int k0 = 0; k0 < 512; k0 += 32) {
    __syncthreads();
    #pragma unroll
    for (int rep = 0; rep < 2; ++rep) {
      int q = tid + rep * 256;   // 512 chunks of 8 f16
      int row = q >> 2, seg = q & 3;
      *(half8_t*)(sA + row * ALD + seg * 8) =
          *(const half8_t*)(A + (size_t)(m0 + row) * 512 + k0 + seg * 8);
      *(half8_t*)(sB + row * ALD + seg * 8) =
          *(const half8_t*)(B + (size_t)(n0 + row) * 512 + k0 + seg * 8);
    }
    __syncthreads();
    half8_t afr[4], bfr[4];
    #pragma unroll
    for (int i = 0; i < 4; ++i) {
      afr[i] = *(const half8_t*)(sA + (wm * 64 + i * 16 + rA) * ALD + q8 * 8);
      bfr[i] = *(const half8_t*)(sB + (wn * 64 + i * 16 + rA) * ALD + q8 * 8);
    }
    #pragma unroll
    for (int i = 0; i < 4; ++i)
      #pragma unroll
      for (int j = 0; j < 4; ++j)
        acc[i][j] = __builtin_amdgcn_mfma_f32_16x16x32_f16(afr[i], bfr[j], acc[i][j], 0, 0, 0);
  }
  // epilogue: bias add, store, per-row tile max (over this block's 128 cols)
  #pragma unroll
  for (int i = 0; i < 4; ++i) {
    #pragma unroll
    for (int p = 0; p < 4; ++p) {
      int m_loc = wm * 64 + i * 16 + q8 * 4 + p;
      int m = m0 + m_loc;
      float vmax = -3.4e38f;
      float vs[4];
      #pragma unroll
      for (int j = 0; j < 4; ++j) {
        int n_loc = wn * 64 + j * 16 + rA;
        float v = acc[i][j][p] + bias[n0 + n_loc];
        vs[j] = v;
        vmax = fmaxf(vmax, v);
      }
      if (m < 2016) {
        int t = m >> 5, bb = m & 31;
        float* orow = out + (size_t)(bb * 63 + t) * 32000 + n0;
        #pragma unroll
        for (int j = 0; j < 4; ++j) orow[wn * 64 + j * 16 + rA] = vs[j];
      }
      #pragma unroll
      for (int o = 1; o < 16; o <<= 1) vmax = fmaxf(vmax, __shfl_xor(vmax, o));
      if (rA == 0) redv[m_loc * 2 + wn] = vmax;
    }
  }
  __syncthreads();
  if (tid < 128) {
    int m = m0 + tid;
    if (m < 2016) {
      float bv = fmaxf(redv[tid * 2], redv[tid * 2 + 1]);
      tmv[(size_t)m * 256 + nb] = bv;
    }
  }
}

// ---------------- K5: exact max/argmax fixup (1 wave per (b,t) row) --------
__global__ void k_final(const float* __restrict__ tmv, const float* __restrict__ HallT,
                        const float* __restrict__ Wout, const float* __restrict__ bias,
                        const float* __restrict__ logits,
                        float* __restrict__ probs, float* __restrict__ preds) {
  int m = blockIdx.x;  // 0..2015, m = t*32 + b
  int t = m >> 5, b = m & 31;
  int lane = threadIdx.x;
  float mx = -3.4e38f;
  for (int nb = lane; nb < 250; nb += 64) mx = fmaxf(mx, tmv[(size_t)m * 256 + nb]);
  #pragma unroll
  for (int o = 1; o < 64; o <<= 1) mx = fmaxf(mx, __shfl_xor(mx, o));
  const float* hrow = HallT + (size_t)t * 16384 + b;
  float hl[8];
  float s2 = 0.f;
  #pragma unroll
  for (int i = 0; i < 8; ++i) {
    float hv = hrow[(lane * 8 + i) * 32];
    hl[i] = hv;
    s2 += hv * hv;
  }
  #pragma unroll
  for (int o = 1; o < 64; o <<= 1) s2 += __shfl_xor(s2, o);
  float marg = 0.0016f * sqrtf(s2) + 3e-4f;
  float thr = mx - 2.f * marg;
  float bestv = -3.4e38f;
  int besti = 0x7fffffff;
  const float* lrow = logits + (size_t)(b * 63 + t) * 32000;
  for (int nb = 0; nb < 250; ++nb) {
    if (tmv[(size_t)m * 256 + nb] < thr) continue;
    #pragma unroll
    for (int rep = 0; rep < 2; ++rep) {
      int n = nb * 128 + rep * 64 + lane;
      float av = lrow[n];
      unsigned long long mask = __ballot(av >= thr);
      while (mask) {
        int ln = __ffsll((unsigned long long)mask) - 1;
        mask &= mask - 1;
        int nn = __shfl(n, ln);
        const float* wr = Wout + (size_t)nn * 512;
        float p = 0.f;
        #pragma unroll
        for (int i = 0; i < 8; ++i) p += hl[i] * wr[lane * 8 + i];
        #pragma unroll
        for (int o = 1; o < 64; o <<= 1) p += __shfl_xor(p, o);
        p += bias[nn];
        if (p > bestv || (p == bestv && nn < besti)) { bestv = p; besti = nn; }
      }
    }
  }
  if (lane == 0) {
    probs[b * 63 + t] = bestv;
    preds[b * 63 + t] = (float)besti;
  }
}

// ---------------------------------------------------------------------------
extern "C" void kernel_launch(void* const* d_in, const int* in_sizes, int n_in,
                              void* d_out, int out_size, void* d_ws, size_t ws_size,
                              hipStream_t stream) {
  const float* enc   = (const float*)d_in[0];
  const int*   caps  = (const int*)d_in[1];
  const float* emb   = (const float*)d_in[2];
  const float* W_ih  = (const float*)d_in[3];
  const float* W_hh  = (const float*)d_in[4];
  const float* b_ih  = (const float*)d_in[5];
  const float* b_hh  = (const float*)d_in[6];
  const float* W_out = (const float*)d_in[7];
  const float* b_out = (const float*)d_in[8];
  float* out = (float*)d_out;

  // ws layout (bytes)
  char* ws = (char*)d_ws;
  const size_t off_gin  = 0;                       // 64*2048*32 f32 = 16 MB
  const size_t off_gxe  = 16777216;                // 32*2048 f32
  const size_t off_hall = off_gxe + 262144;        // 64*16384 f32 = 4 MB  [t][k][b]
  const size_t off_hf16 = off_hall + 4194304;      // 2048*512 f16 = 2 MB  [m][k]
  const size_t off_c    = off_hf16 + 2097152;      // 16384 f32
  const size_t off_hz   = off_c + 65536;           // 16384 f32 (zeros)
  const size_t off_tmv  = off_hz + 65536;          // 2048*256 f32 = 2 MB
  const size_t off_wf16 = off_tmv + 2097152;       // 32000*512 f16 = 32.768 MB
  const size_t need     = off_wf16 + 32768000;
  if (ws_size < need) {
    fprintf(stderr, "kernel_launch: ws_size %zu < needed %zu\n", ws_size, need);
    return;
  }
  float*     ginT  = (float*)(ws + off_gin);
  float*     gxe   = (float*)(ws + off_gxe);
  float*     HallT = (float*)(ws + off_hall);
  _Float16*  Hf16  = (_Float16*)(ws + off_hf16);
  float*     cT    = (float*)(ws + off_c);
  float*     hzero = (float*)(ws + off_hz);
  float*     tmv   = (float*)(ws + off_tmv);
  _Float16*  Wf16  = (_Float16*)(ws + off_wf16);
  // transient split-f16 scratch inside the (not-yet-written) Wf16 region:
  _Float16*  Xhi = Wf16;                 // 2048*512 f16 = 2 MB
  _Float16*  Xlo = Xhi + 2048 * 512;
  _Float16*  Whi = Xlo + 2048 * 512;
  _Float16*  Wlo = Whi + 2048 * 512;     // total 8 MB < 32.77 MB region

  hipMemsetAsync(ws + off_c, 0, 131072, stream);   // c0 and h0 = 0

  k_gxe<<<128, 256, 0, stream>>>(enc, W_ih, b_ih, b_hh, gxe);
  k_prep_w<<<1024, 256, 0, stream>>>(W_ih, Whi, Wlo);
  k_prep_x<<<512, 256, 0, stream>>>(emb, caps, Xhi, Xlo);
  k_gin_mfma<<<dim3(16, 16), 256, 0, stream>>>(Whi, Wlo, Xhi, Xlo, gxe, ginT);
  // overwrites the split scratch — must come after k_gin_mfma:
  k_f32_to_f16<<<8000, 256, 0, stream>>>(W_out, Wf16);

  for (int t = 0; t < 63; ++t) {
    const float* hprev = (t == 0) ? hzero : (HallT + (size_t)(t - 1) * 16384);
    k_step<<<256, 256, 0, stream>>>(hprev, W_hh, ginT + (size_t)t * 65536, cT,
                                    HallT + (size_t)t * 16384, Hf16 + (size_t)t * 16384);
  }

  k_logits<<<dim3(250, 16), 256, 0, stream>>>(Hf16, Wf16, b_out, out, tmv);

  float* probs = out + (size_t)2016 * 32000;
  float* preds = probs + 2016;
  k_final<<<2016, 64, 0, stream>>>(tmv, HallT, W_out, b_out, out, probs, preds);
}